// Round 7
// baseline (255.832 us; speedup 1.0000x reference)
//
#include <hip/hip_runtime.h>
#include <hip/hip_bf16.h>

typedef __attribute__((ext_vector_type(8))) short short8v;
typedef __attribute__((ext_vector_type(4))) float floatx4;

__device__ __forceinline__ unsigned short f2bf(float f) {
    unsigned b = __float_as_uint(f);
    b = (b + 0x7fffu + ((b >> 16) & 1u)) >> 16;
    return (unsigned short)b;
}
__device__ __forceinline__ float b2f(unsigned short u) {
    return __uint_as_float((unsigned)u << 16);
}

// ------ fused front: fp32->bf16 of x, W_gat, W_lin  +  dst histogram --------
__global__ void k_prep(const float* __restrict__ s0, unsigned short* __restrict__ d0, int n0,
                       const float* __restrict__ s1, unsigned short* __restrict__ d1, int n1,
                       const float* __restrict__ s2, unsigned short* __restrict__ d2, int n2,
                       const int* __restrict__ ei, int* __restrict__ cnt, int E, int EE) {
    int nconv = n0 + n1 + n2;
    int total = nconv + EE;
    int i = blockIdx.x * blockDim.x + threadIdx.x;
    int stride = gridDim.x * blockDim.x;
    for (; i < total; i += stride) {
        if (i < nconv) {
            const float* s; unsigned short* d; int j;
            if (i < n0) { s = s0; d = d0; j = i; }
            else if (i < n0 + n1) { s = s1; d = d1; j = i - n0; }
            else { s = s2; d = d2; j = i - n0 - n1; }
            float4 v = reinterpret_cast<const float4*>(s)[j];
            ushort4 o;
            o.x = f2bf(v.x); o.y = f2bf(v.y); o.z = f2bf(v.z); o.w = f2bf(v.w);
            reinterpret_cast<ushort4*>(d)[j] = o;
        } else {
            int e = i - nconv;
            int dst = (e < E) ? ei[E + e] : e - E;
            atomicAdd(&cnt[dst], 1);
        }
    }
}

// ------ GEMM1 + fused attention epilogue ------------------------------------
// hb[M,256] = bf16(A @ B); a_src/a_dst[M,8] = head-wise dot(h, att_*).
// One block per 64-row stripe; A fragments live in registers across the
// 4 column-tiles (A read ONCE from HBM), B tile staged in LDS per ntile.
__launch_bounds__(256)
__global__ void k_gemm1(const unsigned short* __restrict__ A,
                        const unsigned short* __restrict__ B,
                        const float* __restrict__ att_src, const float* __restrict__ att_dst,
                        unsigned short* __restrict__ hb,
                        float* __restrict__ a_src, float* __restrict__ a_dst, int M) {
    __shared__ unsigned short BsT[64 * 264];  // [col][k], stride 264
    const int tid = threadIdx.x;
    const int tM = blockIdx.x * 64;
    const int w  = tid >> 6;
    const int l  = tid & 63;
    const int lg = l >> 4;
    const int lr = l & 15;

    // load A fragments once (8 k-tiles of 32)
    int rowA = tM + w * 16 + lr;
    if (rowA > M - 1) rowA = M - 1;
    const unsigned short* Arow = A + (size_t)rowA * 256 + lg * 8;
    short8v av[8];
#pragma unroll
    for (int kt = 0; kt < 8; ++kt)
        av[kt] = *reinterpret_cast<const short8v*>(Arow + kt * 32);

    for (int nt = 0; nt < 4; ++nt) {
        if (nt) __syncthreads();   // protect BsT from previous iteration's readers
        for (int it = 0; it < 8; ++it) {
            int f8 = it * 256 + tid;
            int k = f8 >> 3;
            int c0 = (f8 & 7) * 8;
            short8v v = *reinterpret_cast<const short8v*>(B + (size_t)k * 256 + nt * 64 + c0);
#pragma unroll
            for (int j = 0; j < 8; ++j)
                BsT[(c0 + j) * 264 + k] = (unsigned short)v[j];
        }
        __syncthreads();

        floatx4 acc[4] = {};
#pragma unroll
        for (int kt = 0; kt < 8; ++kt) {
#pragma unroll
            for (int n = 0; n < 4; ++n) {
                short8v bv = *reinterpret_cast<const short8v*>(&BsT[(n * 16 + lr) * 264 + kt * 32 + lg * 8]);
                acc[n] = __builtin_amdgcn_mfma_f32_16x16x32_bf16(av[kt], bv, acc[n], 0, 0, 0);
            }
        }

        // epilogue: bf16 h-tile write + attention partials
        float ps[2][4] = {}, pd[2][4] = {};
#pragma unroll
        for (int n = 0; n < 4; ++n) {
            int hd2 = n >> 1;                      // head within this ntile (0/1)
            float asv = att_src[(nt * 2 + hd2) * 32 + (n & 1) * 16 + lr];
            float adv = att_dst[(nt * 2 + hd2) * 32 + (n & 1) * 16 + lr];
            int col = nt * 64 + n * 16 + lr;
#pragma unroll
            for (int r = 0; r < 4; ++r) {
                int row = tM + w * 16 + lg * 4 + r;  // C/D: row=(lane>>4)*4+reg
                float v = acc[n][r];
                if (row < M) hb[(size_t)row * 256 + col] = f2bf(v);
                ps[hd2][r] += v * asv;
                pd[hd2][r] += v * adv;
            }
        }
        // reduce over the 16 lanes (lr) of each row-group
#pragma unroll
        for (int off = 1; off < 16; off <<= 1) {
#pragma unroll
            for (int hd2 = 0; hd2 < 2; ++hd2)
#pragma unroll
                for (int r = 0; r < 4; ++r) {
                    ps[hd2][r] += __shfl_xor(ps[hd2][r], off, 64);
                    pd[hd2][r] += __shfl_xor(pd[hd2][r], off, 64);
                }
        }
        if (lr == 0) {
#pragma unroll
            for (int hd2 = 0; hd2 < 2; ++hd2)
#pragma unroll
                for (int r = 0; r < 4; ++r) {
                    int row = tM + w * 16 + lg * 4 + r;
                    if (row < M) {
                        a_src[(size_t)row * 8 + nt * 2 + hd2] = ps[hd2][r];
                        a_dst[(size_t)row * 8 + nt * 2 + hd2] = pd[hd2][r];
                    }
                }
        }
    }
}

// ------ generic bf16 MFMA GEMM (used for GEMM2): C fp32 = A@B + bias --------
__launch_bounds__(256)
__global__ void k_gemm(const unsigned short* __restrict__ A,
                       const unsigned short* __restrict__ B,
                       float* __restrict__ C,
                       const float* __restrict__ bias,
                       int M, int NC) {
    __shared__ unsigned short BsT[64 * 264];
    const int tid = threadIdx.x;
    const int ntile = blockIdx.y;
    const int tM = blockIdx.x * 64;

    for (int it = 0; it < 8; ++it) {
        int f8 = it * 256 + tid;
        int k = f8 >> 3;
        int c0 = (f8 & 7) * 8;
        short8v v = *reinterpret_cast<const short8v*>(B + (size_t)k * NC + ntile * 64 + c0);
#pragma unroll
        for (int j = 0; j < 8; ++j)
            BsT[(c0 + j) * 264 + k] = (unsigned short)v[j];
    }
    __syncthreads();

    const int w  = tid >> 6;
    const int l  = tid & 63;
    const int lg = l >> 4;
    const int lr = l & 15;

    floatx4 acc[4] = {};
    int rowA = tM + w * 16 + lr;
    if (rowA > M - 1) rowA = M - 1;
    const unsigned short* Arow = A + (size_t)rowA * 256 + lg * 8;

#pragma unroll
    for (int kt = 0; kt < 8; ++kt) {
        short8v av = *reinterpret_cast<const short8v*>(Arow + kt * 32);
#pragma unroll
        for (int n = 0; n < 4; ++n) {
            short8v bv = *reinterpret_cast<const short8v*>(&BsT[(n * 16 + lr) * 264 + kt * 32 + lg * 8]);
            acc[n] = __builtin_amdgcn_mfma_f32_16x16x32_bf16(av, bv, acc[n], 0, 0, 0);
        }
    }
#pragma unroll
    for (int n = 0; n < 4; ++n) {
        int col = ntile * 64 + n * 16 + lr;
        float badd = bias ? bias[col] : 0.0f;
#pragma unroll
        for (int r = 0; r < 4; ++r) {
            int row = tM + w * 16 + lg * 4 + r;
            if (row < M) C[(size_t)row * NC + col] = acc[n][r] + badd;
        }
    }
}

// ---------------- hierarchical exclusive scan over cnt[N] -------------------
#define SCAN_NB 256
__launch_bounds__(256)
__global__ void k_scan_a(const int* __restrict__ cnt, int* __restrict__ bsum, int N) {
    __shared__ int sh[256];
    int b = blockIdx.x, t = threadIdx.x;
    int chunk = (N + SCAN_NB - 1) / SCAN_NB;
    int idx = b * chunk + t;
    sh[t] = (t < chunk && idx < N) ? cnt[idx] : 0;
    __syncthreads();
    for (int off = 128; off > 0; off >>= 1) {
        if (t < off) sh[t] += sh[t + off];
        __syncthreads();
    }
    if (t == 0) bsum[b] = sh[0];
}
// fused: scan block sums in-LDS (redundant per block) + per-chunk scan
__launch_bounds__(256)
__global__ void k_scan_bc(const int* __restrict__ cnt, const int* __restrict__ bsum,
                          int* __restrict__ row_start, int* __restrict__ cursor, int N) {
    __shared__ int shb[256];
    __shared__ int sh[256];
    int b = blockIdx.x, t = threadIdx.x;
    shb[t] = bsum[t];
    __syncthreads();
    for (int off = 1; off < 256; off <<= 1) {
        int v = (t >= off) ? shb[t - off] : 0;
        __syncthreads();
        shb[t] += v;
        __syncthreads();
    }
    int boff = (b == 0) ? 0 : shb[b - 1];

    int chunk = (N + SCAN_NB - 1) / SCAN_NB;
    int idx = b * chunk + t;
    int v = (t < chunk && idx < N) ? cnt[idx] : 0;
    sh[t] = v;
    __syncthreads();
    for (int off = 1; off < 256; off <<= 1) {
        int u = (t >= off) ? sh[t - off] : 0;
        __syncthreads();
        sh[t] += u;
        __syncthreads();
    }
    if (t < chunk && idx < N) {
        int ex = boff + sh[t] - v;
        row_start[idx] = ex;
        cursor[idx] = ex;
    }
}

// ---------------- scatter edges into dst-sorted order ----------------
__global__ void k_scatter(const int* __restrict__ ei, int* __restrict__ cursor,
                          int* __restrict__ sorted_src, int E, int EE) {
    int e = blockIdx.x * blockDim.x + threadIdx.x;
    if (e >= EE) return;
    int src, dst;
    if (e < E) { src = ei[e]; dst = ei[E + e]; } else { src = dst = e - E; }
    int pos = atomicAdd(&cursor[dst], 1);
    sorted_src[pos] = src;
}

// ---------------- fused aggregate: softmax-weighted sum + bias + relu -> bf16
__launch_bounds__(256)
__global__ void k_agg(const int* __restrict__ row_start, const int* __restrict__ row_end,
                      const int* __restrict__ sorted_src,
                      const float* __restrict__ a_src, const float* __restrict__ a_dst,
                      const unsigned short* __restrict__ hb,
                      const float* __restrict__ bias_gat,
                      unsigned short* __restrict__ gb, int N) {
    int n = blockIdx.x * 4 + (threadIdx.x >> 6);
    if (n >= N) return;
    int lane = threadIdx.x & 63;
    int hd = lane >> 3;
    int start = row_start[n], end = row_end[n];
    float ad = a_dst[(size_t)n * 8 + hd];
    float ax = 0.f, ay = 0.f, az = 0.f, aw = 0.f, den = 0.f;
    float bx = 0.f, by = 0.f, bz = 0.f, bw = 0.f, den2 = 0.f;
    for (int j0 = start; j0 < end; j0 += 64) {
        int idx = j0 + lane;
        int sv = (idx < end) ? sorted_src[idx] : 0;
        int cnt = end - j0; if (cnt > 64) cnt = 64;
        int jj = 0;
        for (; jj + 1 < cnt; jj += 2) {
            int s0 = __shfl(sv, jj);
            int s1 = __shfl(sv, jj + 1);
            float v0 = a_src[(size_t)s0 * 8 + hd] + ad;
            float v1 = a_src[(size_t)s1 * 8 + hd] + ad;
            v0 = v0 > 0.f ? v0 : 0.2f * v0;
            v1 = v1 > 0.f ? v1 : 0.2f * v1;
            float e0 = __expf(v0);
            float e1 = __expf(v1);
            ushort4 h0 = *reinterpret_cast<const ushort4*>(hb + (size_t)s0 * 256 + lane * 4);
            ushort4 h1 = *reinterpret_cast<const ushort4*>(hb + (size_t)s1 * 256 + lane * 4);
            den  += e0; den2 += e1;
            ax += e0 * b2f(h0.x); ay += e0 * b2f(h0.y);
            az += e0 * b2f(h0.z); aw += e0 * b2f(h0.w);
            bx += e1 * b2f(h1.x); by += e1 * b2f(h1.y);
            bz += e1 * b2f(h1.z); bw += e1 * b2f(h1.w);
        }
        if (jj < cnt) {
            int s0 = __shfl(sv, jj);
            float v0 = a_src[(size_t)s0 * 8 + hd] + ad;
            v0 = v0 > 0.f ? v0 : 0.2f * v0;
            float e0 = __expf(v0);
            ushort4 h0 = *reinterpret_cast<const ushort4*>(hb + (size_t)s0 * 256 + lane * 4);
            den += e0;
            ax += e0 * b2f(h0.x); ay += e0 * b2f(h0.y);
            az += e0 * b2f(h0.z); aw += e0 * b2f(h0.w);
        }
    }
    float inv = 1.0f / (den + den2 + 1e-16f);
    float4 b4 = *reinterpret_cast<const float4*>(bias_gat + lane * 4);
    ushort4 o;
    o.x = f2bf(fmaxf((ax + bx) * inv + b4.x, 0.f));
    o.y = f2bf(fmaxf((ay + by) * inv + b4.y, 0.f));
    o.z = f2bf(fmaxf((az + bz) * inv + b4.z, 0.f));
    o.w = f2bf(fmaxf((aw + bw) * inv + b4.w, 0.f));
    reinterpret_cast<ushort4*>(gb)[(size_t)n * 64 + lane] = o;
}

extern "C" void kernel_launch(void* const* d_in, const int* in_sizes, int n_in,
                              void* d_out, int out_size, void* d_ws, size_t ws_size,
                              hipStream_t stream) {
    const float* x        = (const float*)d_in[0];
    const int*   ei       = (const int*)d_in[1];
    const float* W_gat    = (const float*)d_in[2];
    const float* att_src  = (const float*)d_in[3];
    const float* att_dst  = (const float*)d_in[4];
    const float* bias_gat = (const float*)d_in[5];
    const float* W_lin    = (const float*)d_in[6];
    const float* b_lin    = (const float*)d_in[7];
    float* out = (float*)d_out;

    const int N  = in_sizes[0] / 256;   // 50000
    const int E  = in_sizes[1] / 2;     // 800000
    const int EE = E + N;

    char* ws = (char*)d_ws;
    size_t off = 0;
    auto alloc = [&](size_t bytes) -> void* {
        void* p = ws + off;
        off = (off + bytes + 255) & ~(size_t)255;
        return p;
    };
    unsigned short* hb       = (unsigned short*)alloc((size_t)N * 256 * 2);
    float*          a_srcv   = (float*)alloc((size_t)N * 8 * 4);
    float*          a_dstv   = (float*)alloc((size_t)N * 8 * 4);
    int*            cnt      = (int*)alloc((size_t)N * 4);
    int*            rowst    = (int*)alloc((size_t)N * 4);
    int*            cursor   = (int*)alloc((size_t)N * 4);
    int*            bsum     = (int*)alloc(SCAN_NB * 4);
    int*            ssrc     = (int*)alloc((size_t)EE * 4);
    unsigned short* xb       = (unsigned short*)alloc((size_t)N * 256 * 2);  // reused as gb
    unsigned short* wb       = (unsigned short*)alloc(256 * 256 * 2);
    unsigned short* wlb      = (unsigned short*)alloc(256 * 64 * 2);

    hipMemsetAsync(cnt, 0, (size_t)N * 4, stream);

    // fused conversions + histogram
    k_prep<<<2048, 256, 0, stream>>>(x, xb, N * 256 / 4,
                                     W_gat, wb, 256 * 256 / 4,
                                     W_lin, wlb, 256 * 64 / 4,
                                     ei, cnt, E, EE);

    // counting-sort scan + scatter
    k_scan_a<<<SCAN_NB, 256, 0, stream>>>(cnt, bsum, N);
    k_scan_bc<<<SCAN_NB, 256, 0, stream>>>(cnt, bsum, rowst, cursor, N);
    k_scatter<<<(EE + 255) / 256, 256, 0, stream>>>(ei, cursor, ssrc, E, EE);

    // GEMM1 + fused attention coefficients
    k_gemm1<<<(N + 63) / 64, 256, 0, stream>>>(xb, wb, att_src, att_dst,
                                               hb, a_srcv, a_dstv, N);

    // fused segment softmax + aggregate + bias + relu -> bf16 (into xb as gb)
    k_agg<<<(N + 3) / 4, 256, 0, stream>>>(rowst, cursor, ssrc, a_srcv, a_dstv, hb,
                                           bias_gat, xb, N);

    // GEMM2: out = g @ W_lin + b_lin
    dim3 g2((N + 63) / 64, 1);
    k_gemm<<<g2, 256, 0, stream>>>(xb, wlb, out, b_lin, N, 64);
}

// Round 8
// 236.010 us; speedup vs baseline: 1.0840x; 1.0840x over previous
//
#include <hip/hip_runtime.h>
#include <hip/hip_bf16.h>

typedef __attribute__((ext_vector_type(8))) short short8v;
typedef __attribute__((ext_vector_type(4))) float floatx4;

__device__ __forceinline__ unsigned short f2bf(float f) {
    unsigned b = __float_as_uint(f);
    b = (b + 0x7fffu + ((b >> 16) & 1u)) >> 16;
    return (unsigned short)b;
}
__device__ __forceinline__ float b2f(unsigned short u) {
    return __uint_as_float((unsigned)u << 16);
}

// ------ fused front: fp32->bf16 of x, W_gat, W_lin  +  dst histogram --------
__global__ void k_prep(const float* __restrict__ s0, unsigned short* __restrict__ d0, int n0,
                       const float* __restrict__ s1, unsigned short* __restrict__ d1, int n1,
                       const float* __restrict__ s2, unsigned short* __restrict__ d2, int n2,
                       const int* __restrict__ ei, int* __restrict__ cnt, int E, int EE) {
    int nconv = n0 + n1 + n2;
    int total = nconv + EE;
    int i = blockIdx.x * blockDim.x + threadIdx.x;
    int stride = gridDim.x * blockDim.x;
    for (; i < total; i += stride) {
        if (i < nconv) {
            const float* s; unsigned short* d; int j;
            if (i < n0) { s = s0; d = d0; j = i; }
            else if (i < n0 + n1) { s = s1; d = d1; j = i - n0; }
            else { s = s2; d = d2; j = i - n0 - n1; }
            float4 v = reinterpret_cast<const float4*>(s)[j];
            ushort4 o;
            o.x = f2bf(v.x); o.y = f2bf(v.y); o.z = f2bf(v.z); o.w = f2bf(v.w);
            reinterpret_cast<ushort4*>(d)[j] = o;
        } else {
            int e = i - nconv;
            int dst = (e < E) ? ei[E + e] : e - E;
            atomicAdd(&cnt[dst], 1);
        }
    }
}

// ------ GEMM1 (parallel col-tiles) + fused attention epilogue ---------------
// grid (row_stripes, 4). Block (r,nt): hb[64 rows, cols nt*64..+64] and
// a_src/a_dst for heads {2nt, 2nt+1} of those rows.
__launch_bounds__(256)
__global__ void k_gemm1(const unsigned short* __restrict__ A,
                        const unsigned short* __restrict__ B,
                        const float* __restrict__ att_src, const float* __restrict__ att_dst,
                        unsigned short* __restrict__ hb,
                        float* __restrict__ a_src, float* __restrict__ a_dst, int M) {
    __shared__ unsigned short BsT[64 * 264];  // [col][k], stride 264
    const int tid = threadIdx.x;
    const int nt = blockIdx.y;
    const int tM = blockIdx.x * 64;

    for (int it = 0; it < 8; ++it) {
        int f8 = it * 256 + tid;
        int k = f8 >> 3;
        int c0 = (f8 & 7) * 8;
        short8v v = *reinterpret_cast<const short8v*>(B + (size_t)k * 256 + nt * 64 + c0);
#pragma unroll
        for (int j = 0; j < 8; ++j)
            BsT[(c0 + j) * 264 + k] = (unsigned short)v[j];
    }
    __syncthreads();

    const int w  = tid >> 6;
    const int l  = tid & 63;
    const int lg = l >> 4;
    const int lr = l & 15;

    floatx4 acc[4] = {};
    int rowA = tM + w * 16 + lr;
    if (rowA > M - 1) rowA = M - 1;
    const unsigned short* Arow = A + (size_t)rowA * 256 + lg * 8;

#pragma unroll
    for (int kt = 0; kt < 8; ++kt) {
        short8v av = *reinterpret_cast<const short8v*>(Arow + kt * 32);
#pragma unroll
        for (int n = 0; n < 4; ++n) {
            short8v bv = *reinterpret_cast<const short8v*>(&BsT[(n * 16 + lr) * 264 + kt * 32 + lg * 8]);
            acc[n] = __builtin_amdgcn_mfma_f32_16x16x32_bf16(av, bv, acc[n], 0, 0, 0);
        }
    }

    // epilogue: bf16 h-tile write + attention partials for this tile's 2 heads
    float ps[2][4] = {}, pd[2][4] = {};
#pragma unroll
    for (int n = 0; n < 4; ++n) {
        int hd2 = n >> 1;                       // head within tile (0/1)
        float asv = att_src[(nt * 2 + hd2) * 32 + (n & 1) * 16 + lr];
        float adv = att_dst[(nt * 2 + hd2) * 32 + (n & 1) * 16 + lr];
        int col = nt * 64 + n * 16 + lr;
#pragma unroll
        for (int r = 0; r < 4; ++r) {
            int row = tM + w * 16 + lg * 4 + r;  // C/D: row=(lane>>4)*4+reg
            float v = acc[n][r];
            if (row < M) hb[(size_t)row * 256 + col] = f2bf(v);
            ps[hd2][r] += v * asv;
            pd[hd2][r] += v * adv;
        }
    }
#pragma unroll
    for (int off = 1; off < 16; off <<= 1) {
#pragma unroll
        for (int hd2 = 0; hd2 < 2; ++hd2)
#pragma unroll
            for (int r = 0; r < 4; ++r) {
                ps[hd2][r] += __shfl_xor(ps[hd2][r], off, 64);
                pd[hd2][r] += __shfl_xor(pd[hd2][r], off, 64);
            }
    }
    if (lr == 0) {
#pragma unroll
        for (int hd2 = 0; hd2 < 2; ++hd2)
#pragma unroll
            for (int r = 0; r < 4; ++r) {
                int row = tM + w * 16 + lg * 4 + r;
                if (row < M) {
                    a_src[(size_t)row * 8 + nt * 2 + hd2] = ps[hd2][r];
                    a_dst[(size_t)row * 8 + nt * 2 + hd2] = pd[hd2][r];
                }
            }
    }
}

// ------ generic bf16 MFMA GEMM (GEMM2): C fp32 = A@B + bias -----------------
__launch_bounds__(256)
__global__ void k_gemm(const unsigned short* __restrict__ A,
                       const unsigned short* __restrict__ B,
                       float* __restrict__ C,
                       const float* __restrict__ bias,
                       int M, int NC) {
    __shared__ unsigned short BsT[64 * 264];
    const int tid = threadIdx.x;
    const int ntile = blockIdx.y;
    const int tM = blockIdx.x * 64;

    for (int it = 0; it < 8; ++it) {
        int f8 = it * 256 + tid;
        int k = f8 >> 3;
        int c0 = (f8 & 7) * 8;
        short8v v = *reinterpret_cast<const short8v*>(B + (size_t)k * NC + ntile * 64 + c0);
#pragma unroll
        for (int j = 0; j < 8; ++j)
            BsT[(c0 + j) * 264 + k] = (unsigned short)v[j];
    }
    __syncthreads();

    const int w  = tid >> 6;
    const int l  = tid & 63;
    const int lg = l >> 4;
    const int lr = l & 15;

    floatx4 acc[4] = {};
    int rowA = tM + w * 16 + lr;
    if (rowA > M - 1) rowA = M - 1;
    const unsigned short* Arow = A + (size_t)rowA * 256 + lg * 8;

#pragma unroll
    for (int kt = 0; kt < 8; ++kt) {
        short8v av = *reinterpret_cast<const short8v*>(Arow + kt * 32);
#pragma unroll
        for (int n = 0; n < 4; ++n) {
            short8v bv = *reinterpret_cast<const short8v*>(&BsT[(n * 16 + lr) * 264 + kt * 32 + lg * 8]);
            acc[n] = __builtin_amdgcn_mfma_f32_16x16x32_bf16(av, bv, acc[n], 0, 0, 0);
        }
    }
#pragma unroll
    for (int n = 0; n < 4; ++n) {
        int col = ntile * 64 + n * 16 + lr;
        float badd = bias ? bias[col] : 0.0f;
#pragma unroll
        for (int r = 0; r < 4; ++r) {
            int row = tM + w * 16 + lg * 4 + r;
            if (row < M) C[(size_t)row * NC + col] = acc[n][r] + badd;
        }
    }
}

// ---------------- hierarchical exclusive scan over cnt[N] -------------------
#define SCAN_NB 256
__launch_bounds__(256)
__global__ void k_scan_a(const int* __restrict__ cnt, int* __restrict__ bsum, int N) {
    __shared__ int sh[256];
    int b = blockIdx.x, t = threadIdx.x;
    int chunk = (N + SCAN_NB - 1) / SCAN_NB;
    int idx = b * chunk + t;
    sh[t] = (t < chunk && idx < N) ? cnt[idx] : 0;
    __syncthreads();
    for (int off = 128; off > 0; off >>= 1) {
        if (t < off) sh[t] += sh[t + off];
        __syncthreads();
    }
    if (t == 0) bsum[b] = sh[0];
}
__launch_bounds__(256)
__global__ void k_scan_bc(const int* __restrict__ cnt, const int* __restrict__ bsum,
                          int* __restrict__ row_start, int* __restrict__ cursor, int N) {
    __shared__ int shb[256];
    __shared__ int sh[256];
    int b = blockIdx.x, t = threadIdx.x;
    shb[t] = bsum[t];
    __syncthreads();
    for (int off = 1; off < 256; off <<= 1) {
        int v = (t >= off) ? shb[t - off] : 0;
        __syncthreads();
        shb[t] += v;
        __syncthreads();
    }
    int boff = (b == 0) ? 0 : shb[b - 1];

    int chunk = (N + SCAN_NB - 1) / SCAN_NB;
    int idx = b * chunk + t;
    int v = (t < chunk && idx < N) ? cnt[idx] : 0;
    sh[t] = v;
    __syncthreads();
    for (int off = 1; off < 256; off <<= 1) {
        int u = (t >= off) ? sh[t - off] : 0;
        __syncthreads();
        sh[t] += u;
        __syncthreads();
    }
    if (t < chunk && idx < N) {
        int ex = boff + sh[t] - v;
        row_start[idx] = ex;
        cursor[idx] = ex;
    }
}

// ---------------- scatter edges into dst-sorted order ----------------
__global__ void k_scatter(const int* __restrict__ ei, int* __restrict__ cursor,
                          int* __restrict__ sorted_src, int E, int EE) {
    int e = blockIdx.x * blockDim.x + threadIdx.x;
    if (e >= EE) return;
    int src, dst;
    if (e < E) { src = ei[e]; dst = ei[E + e]; } else { src = dst = e - E; }
    int pos = atomicAdd(&cursor[dst], 1);
    sorted_src[pos] = src;
}

// ------ fused aggregate: softmax-weighted sum + bias + relu -> bf16 ---------
// one wave per dst node; lane covers 4 channels (head = lane>>3). Edges
// batch-loaded 64-wide, broadcast via shfl; unroll x4 for memory-level par.
__launch_bounds__(256)
__global__ void k_agg(const int* __restrict__ row_start, const int* __restrict__ row_end,
                      const int* __restrict__ sorted_src,
                      const float* __restrict__ a_src, const float* __restrict__ a_dst,
                      const unsigned short* __restrict__ hb,
                      const float* __restrict__ bias_gat,
                      unsigned short* __restrict__ gb, int N) {
    int n = blockIdx.x * 4 + (threadIdx.x >> 6);
    if (n >= N) return;
    int lane = threadIdx.x & 63;
    int hd = lane >> 3;
    int start = row_start[n], end = row_end[n];
    float ad = a_dst[(size_t)n * 8 + hd];
    float ax = 0.f, ay = 0.f, az = 0.f, aw = 0.f, den = 0.f;
    float bx = 0.f, by = 0.f, bz = 0.f, bw = 0.f, den2 = 0.f;
    for (int j0 = start; j0 < end; j0 += 64) {
        int idx = j0 + lane;
        int sv = (idx < end) ? sorted_src[idx] : 0;
        int cnt = end - j0; if (cnt > 64) cnt = 64;
        int jj = 0;
        for (; jj + 3 < cnt; jj += 4) {
            int s0 = __shfl(sv, jj);
            int s1 = __shfl(sv, jj + 1);
            int s2 = __shfl(sv, jj + 2);
            int s3 = __shfl(sv, jj + 3);
            float v0 = a_src[(size_t)s0 * 8 + hd] + ad;
            float v1 = a_src[(size_t)s1 * 8 + hd] + ad;
            float v2 = a_src[(size_t)s2 * 8 + hd] + ad;
            float v3 = a_src[(size_t)s3 * 8 + hd] + ad;
            ushort4 h0 = *reinterpret_cast<const ushort4*>(hb + (size_t)s0 * 256 + lane * 4);
            ushort4 h1 = *reinterpret_cast<const ushort4*>(hb + (size_t)s1 * 256 + lane * 4);
            ushort4 h2 = *reinterpret_cast<const ushort4*>(hb + (size_t)s2 * 256 + lane * 4);
            ushort4 h3 = *reinterpret_cast<const ushort4*>(hb + (size_t)s3 * 256 + lane * 4);
            v0 = v0 > 0.f ? v0 : 0.2f * v0;
            v1 = v1 > 0.f ? v1 : 0.2f * v1;
            v2 = v2 > 0.f ? v2 : 0.2f * v2;
            v3 = v3 > 0.f ? v3 : 0.2f * v3;
            float e0 = __expf(v0), e1 = __expf(v1), e2 = __expf(v2), e3 = __expf(v3);
            den  += e0 + e2; den2 += e1 + e3;
            ax += e0 * b2f(h0.x); ay += e0 * b2f(h0.y);
            az += e0 * b2f(h0.z); aw += e0 * b2f(h0.w);
            bx += e1 * b2f(h1.x); by += e1 * b2f(h1.y);
            bz += e1 * b2f(h1.z); bw += e1 * b2f(h1.w);
            ax += e2 * b2f(h2.x); ay += e2 * b2f(h2.y);
            az += e2 * b2f(h2.z); aw += e2 * b2f(h2.w);
            bx += e3 * b2f(h3.x); by += e3 * b2f(h3.y);
            bz += e3 * b2f(h3.z); bw += e3 * b2f(h3.w);
        }
        for (; jj < cnt; ++jj) {
            int s0 = __shfl(sv, jj);
            float v0 = a_src[(size_t)s0 * 8 + hd] + ad;
            v0 = v0 > 0.f ? v0 : 0.2f * v0;
            float e0 = __expf(v0);
            ushort4 h0 = *reinterpret_cast<const ushort4*>(hb + (size_t)s0 * 256 + lane * 4);
            den += e0;
            ax += e0 * b2f(h0.x); ay += e0 * b2f(h0.y);
            az += e0 * b2f(h0.z); aw += e0 * b2f(h0.w);
        }
    }
    float inv = 1.0f / (den + den2 + 1e-16f);
    float4 b4 = *reinterpret_cast<const float4*>(bias_gat + lane * 4);
    ushort4 o;
    o.x = f2bf(fmaxf((ax + bx) * inv + b4.x, 0.f));
    o.y = f2bf(fmaxf((ay + by) * inv + b4.y, 0.f));
    o.z = f2bf(fmaxf((az + bz) * inv + b4.z, 0.f));
    o.w = f2bf(fmaxf((aw + bw) * inv + b4.w, 0.f));
    reinterpret_cast<ushort4*>(gb)[(size_t)n * 64 + lane] = o;
}

extern "C" void kernel_launch(void* const* d_in, const int* in_sizes, int n_in,
                              void* d_out, int out_size, void* d_ws, size_t ws_size,
                              hipStream_t stream) {
    const float* x        = (const float*)d_in[0];
    const int*   ei       = (const int*)d_in[1];
    const float* W_gat    = (const float*)d_in[2];
    const float* att_src  = (const float*)d_in[3];
    const float* att_dst  = (const float*)d_in[4];
    const float* bias_gat = (const float*)d_in[5];
    const float* W_lin    = (const float*)d_in[6];
    const float* b_lin    = (const float*)d_in[7];
    float* out = (float*)d_out;

    const int N  = in_sizes[0] / 256;   // 50000
    const int E  = in_sizes[1] / 2;     // 800000
    const int EE = E + N;

    char* ws = (char*)d_ws;
    size_t off = 0;
    auto alloc = [&](size_t bytes) -> void* {
        void* p = ws + off;
        off = (off + bytes + 255) & ~(size_t)255;
        return p;
    };
    unsigned short* hb       = (unsigned short*)alloc((size_t)N * 256 * 2);
    float*          a_srcv   = (float*)alloc((size_t)N * 8 * 4);
    float*          a_dstv   = (float*)alloc((size_t)N * 8 * 4);
    int*            cnt      = (int*)alloc((size_t)N * 4);
    int*            rowst    = (int*)alloc((size_t)N * 4);
    int*            cursor   = (int*)alloc((size_t)N * 4);
    int*            bsum     = (int*)alloc(SCAN_NB * 4);
    int*            ssrc     = (int*)alloc((size_t)EE * 4);
    unsigned short* xb       = (unsigned short*)alloc((size_t)N * 256 * 2);  // reused as gb
    unsigned short* wb       = (unsigned short*)alloc(256 * 256 * 2);
    unsigned short* wlb      = (unsigned short*)alloc(256 * 64 * 2);

    hipMemsetAsync(cnt, 0, (size_t)N * 4, stream);

    // fused conversions + histogram
    k_prep<<<2048, 256, 0, stream>>>(x, xb, N * 256 / 4,
                                     W_gat, wb, 256 * 256 / 4,
                                     W_lin, wlb, 256 * 64 / 4,
                                     ei, cnt, E, EE);

    // counting-sort scan + scatter
    k_scan_a<<<SCAN_NB, 256, 0, stream>>>(cnt, bsum, N);
    k_scan_bc<<<SCAN_NB, 256, 0, stream>>>(cnt, bsum, rowst, cursor, N);
    k_scatter<<<(EE + 255) / 256, 256, 0, stream>>>(ei, cursor, ssrc, E, EE);

    // GEMM1 (parallel col-tiles) + fused attention coefficients
    dim3 g1((N + 63) / 64, 4);
    k_gemm1<<<g1, 256, 0, stream>>>(xb, wb, att_src, att_dst, hb, a_srcv, a_dstv, N);

    // fused segment softmax + aggregate + bias + relu -> bf16 (into xb as gb)
    k_agg<<<(N + 3) / 4, 256, 0, stream>>>(rowst, cursor, ssrc, a_srcv, a_dstv, hb,
                                           bias_gat, xb, N);

    // GEMM2: out = g @ W_lin + b_lin
    dim3 g2((N + 63) / 64, 1);
    k_gemm<<<g2, 256, 0, stream>>>(xb, wlb, out, b_lin, N, 64);
}

// Round 9
// 220.404 us; speedup vs baseline: 1.1607x; 1.0708x over previous
//
#include <hip/hip_runtime.h>
#include <hip/hip_bf16.h>

typedef __attribute__((ext_vector_type(8))) short short8v;
typedef __attribute__((ext_vector_type(4))) float floatx4;

__device__ __forceinline__ unsigned short f2bf(float f) {
    unsigned b = __float_as_uint(f);
    b = (b + 0x7fffu + ((b >> 16) & 1u)) >> 16;
    return (unsigned short)b;
}
__device__ __forceinline__ float b2f(unsigned short u) {
    return __uint_as_float((unsigned)u << 16);
}

// LDS B-tile index: [col][k] with k XOR-swizzled so staging writes spread
// across all 32 banks (was a 16-way conflict with plain stride-264).
// XOR touches only bits 3-5 of k => 8-element (16B) reads stay contiguous
// and 16B-aligned.
#define BIDX(col, k) ((col) * 264 + ((k) ^ ((((col) >> 3) & 7) << 3)))

// ------ fused front: fp32->bf16 of x, W_gat, W_lin  +  dst histogram --------
__global__ void k_prep(const float* __restrict__ s0, unsigned short* __restrict__ d0, int n0,
                       const float* __restrict__ s1, unsigned short* __restrict__ d1, int n1,
                       const float* __restrict__ s2, unsigned short* __restrict__ d2, int n2,
                       const int* __restrict__ ei, int* __restrict__ cnt, int E, int EE) {
    int nconv = n0 + n1 + n2;
    int total = nconv + EE;
    int i = blockIdx.x * blockDim.x + threadIdx.x;
    int stride = gridDim.x * blockDim.x;
    for (; i < total; i += stride) {
        if (i < nconv) {
            const float* s; unsigned short* d; int j;
            if (i < n0) { s = s0; d = d0; j = i; }
            else if (i < n0 + n1) { s = s1; d = d1; j = i - n0; }
            else { s = s2; d = d2; j = i - n0 - n1; }
            float4 v = reinterpret_cast<const float4*>(s)[j];
            ushort4 o;
            o.x = f2bf(v.x); o.y = f2bf(v.y); o.z = f2bf(v.z); o.w = f2bf(v.w);
            reinterpret_cast<ushort4*>(d)[j] = o;
        } else {
            int e = i - nconv;
            int dst = (e < E) ? ei[E + e] : e - E;
            atomicAdd(&cnt[dst], 1);
        }
    }
}

// ------ fused: GEMM1 (+attention epilogue) blocks  ||  scatter blocks -------
// blocks [0, GB1): gemm1, bx = b % RB (row stripe), nt = b / RB (col tile).
// blocks [GB1, ...): scatter edges into dst-sorted order.
__launch_bounds__(256)
__global__ void k_gs(const unsigned short* __restrict__ A,
                     const unsigned short* __restrict__ B,
                     const float* __restrict__ att_src, const float* __restrict__ att_dst,
                     unsigned short* __restrict__ hb,
                     float* __restrict__ a_src, float* __restrict__ a_dst,
                     int M, int RB, int GB1,
                     const int* __restrict__ ei, int* __restrict__ cursor,
                     int* __restrict__ sorted_src, int E, int EE) {
    __shared__ unsigned short BsT[64 * 264];
    const int b = blockIdx.x;
    if (b >= GB1) {
        // ---- scatter part ----
        int e = (b - GB1) * 256 + threadIdx.x;
        if (e >= EE) return;
        int src, dst;
        if (e < E) { src = ei[e]; dst = ei[E + e]; } else { src = dst = e - E; }
        int pos = atomicAdd(&cursor[dst], 1);
        sorted_src[pos] = src;
        return;
    }
    // ---- gemm1 part ----
    const int tid = threadIdx.x;
    const int nt = b / RB;
    const int tM = (b - nt * RB) * 64;

    for (int it = 0; it < 8; ++it) {
        int f8 = it * 256 + tid;
        int k = f8 >> 3;
        int c0 = (f8 & 7) * 8;
        short8v v = *reinterpret_cast<const short8v*>(B + (size_t)k * 256 + nt * 64 + c0);
#pragma unroll
        for (int j = 0; j < 8; ++j)
            BsT[BIDX(c0 + j, k)] = (unsigned short)v[j];
    }
    __syncthreads();

    const int w  = tid >> 6;
    const int l  = tid & 63;
    const int lg = l >> 4;
    const int lr = l & 15;

    floatx4 acc[4] = {};
    int rowA = tM + w * 16 + lr;
    if (rowA > M - 1) rowA = M - 1;
    const unsigned short* Arow = A + (size_t)rowA * 256 + lg * 8;

#pragma unroll
    for (int kt = 0; kt < 8; ++kt) {
        short8v av = *reinterpret_cast<const short8v*>(Arow + kt * 32);
#pragma unroll
        for (int n = 0; n < 4; ++n) {
            short8v bv = *reinterpret_cast<const short8v*>(&BsT[BIDX(n * 16 + lr, kt * 32 + lg * 8)]);
            acc[n] = __builtin_amdgcn_mfma_f32_16x16x32_bf16(av, bv, acc[n], 0, 0, 0);
        }
    }

    float ps[2][4] = {}, pd[2][4] = {};
#pragma unroll
    for (int n = 0; n < 4; ++n) {
        int hd2 = n >> 1;
        float asv = att_src[(nt * 2 + hd2) * 32 + (n & 1) * 16 + lr];
        float adv = att_dst[(nt * 2 + hd2) * 32 + (n & 1) * 16 + lr];
        int col = nt * 64 + n * 16 + lr;
#pragma unroll
        for (int r = 0; r < 4; ++r) {
            int row = tM + w * 16 + lg * 4 + r;  // C/D: row=(lane>>4)*4+reg
            float v = acc[n][r];
            if (row < M) hb[(size_t)row * 256 + col] = f2bf(v);
            ps[hd2][r] += v * asv;
            pd[hd2][r] += v * adv;
        }
    }
#pragma unroll
    for (int off = 1; off < 16; off <<= 1) {
#pragma unroll
        for (int hd2 = 0; hd2 < 2; ++hd2)
#pragma unroll
            for (int r = 0; r < 4; ++r) {
                ps[hd2][r] += __shfl_xor(ps[hd2][r], off, 64);
                pd[hd2][r] += __shfl_xor(pd[hd2][r], off, 64);
            }
    }
    if (lr == 0) {
#pragma unroll
        for (int hd2 = 0; hd2 < 2; ++hd2)
#pragma unroll
            for (int r = 0; r < 4; ++r) {
                int row = tM + w * 16 + lg * 4 + r;
                if (row < M) {
                    a_src[(size_t)row * 8 + nt * 2 + hd2] = ps[hd2][r];
                    a_dst[(size_t)row * 8 + nt * 2 + hd2] = pd[hd2][r];
                }
            }
    }
}

// ------ generic bf16 MFMA GEMM (GEMM2): C fp32 = A@B + bias -----------------
__launch_bounds__(256)
__global__ void k_gemm(const unsigned short* __restrict__ A,
                       const unsigned short* __restrict__ B,
                       float* __restrict__ C,
                       const float* __restrict__ bias,
                       int M, int NC) {
    __shared__ unsigned short BsT[64 * 264];
    const int tid = threadIdx.x;
    const int ntile = blockIdx.y;
    const int tM = blockIdx.x * 64;

    for (int it = 0; it < 8; ++it) {
        int f8 = it * 256 + tid;
        int k = f8 >> 3;
        int c0 = (f8 & 7) * 8;
        short8v v = *reinterpret_cast<const short8v*>(B + (size_t)k * NC + ntile * 64 + c0);
#pragma unroll
        for (int j = 0; j < 8; ++j)
            BsT[BIDX(c0 + j, k)] = (unsigned short)v[j];
    }
    __syncthreads();

    const int w  = tid >> 6;
    const int l  = tid & 63;
    const int lg = l >> 4;
    const int lr = l & 15;

    floatx4 acc[4] = {};
    int rowA = tM + w * 16 + lr;
    if (rowA > M - 1) rowA = M - 1;
    const unsigned short* Arow = A + (size_t)rowA * 256 + lg * 8;

#pragma unroll
    for (int kt = 0; kt < 8; ++kt) {
        short8v av = *reinterpret_cast<const short8v*>(Arow + kt * 32);
#pragma unroll
        for (int n = 0; n < 4; ++n) {
            short8v bv = *reinterpret_cast<const short8v*>(&BsT[BIDX(n * 16 + lr, kt * 32 + lg * 8)]);
            acc[n] = __builtin_amdgcn_mfma_f32_16x16x32_bf16(av, bv, acc[n], 0, 0, 0);
        }
    }
#pragma unroll
    for (int n = 0; n < 4; ++n) {
        int col = ntile * 64 + n * 16 + lr;
        float badd = bias ? bias[col] : 0.0f;
#pragma unroll
        for (int r = 0; r < 4; ++r) {
            int row = tM + w * 16 + lg * 4 + r;
            if (row < M) C[(size_t)row * NC + col] = acc[n][r] + badd;
        }
    }
}

// ---------------- hierarchical exclusive scan over cnt[N] -------------------
#define SCAN_NB 256
__launch_bounds__(256)
__global__ void k_scan_a(const int* __restrict__ cnt, int* __restrict__ bsum, int N) {
    __shared__ int sh[256];
    int b = blockIdx.x, t = threadIdx.x;
    int chunk = (N + SCAN_NB - 1) / SCAN_NB;
    int idx = b * chunk + t;
    sh[t] = (t < chunk && idx < N) ? cnt[idx] : 0;
    __syncthreads();
    for (int off = 128; off > 0; off >>= 1) {
        if (t < off) sh[t] += sh[t + off];
        __syncthreads();
    }
    if (t == 0) bsum[b] = sh[0];
}
__launch_bounds__(256)
__global__ void k_scan_bc(const int* __restrict__ cnt, const int* __restrict__ bsum,
                          int* __restrict__ row_start, int* __restrict__ cursor, int N) {
    __shared__ int shb[256];
    __shared__ int sh[256];
    int b = blockIdx.x, t = threadIdx.x;
    shb[t] = bsum[t];
    __syncthreads();
    for (int off = 1; off < 256; off <<= 1) {
        int v = (t >= off) ? shb[t - off] : 0;
        __syncthreads();
        shb[t] += v;
        __syncthreads();
    }
    int boff = (b == 0) ? 0 : shb[b - 1];

    int chunk = (N + SCAN_NB - 1) / SCAN_NB;
    int idx = b * chunk + t;
    int v = (t < chunk && idx < N) ? cnt[idx] : 0;
    sh[t] = v;
    __syncthreads();
    for (int off = 1; off < 256; off <<= 1) {
        int u = (t >= off) ? sh[t - off] : 0;
        __syncthreads();
        sh[t] += u;
        __syncthreads();
    }
    if (t < chunk && idx < N) {
        int ex = boff + sh[t] - v;
        row_start[idx] = ex;
        cursor[idx] = ex;
    }
}

// ------ fused aggregate: softmax-weighted sum + bias + relu -> bf16 ---------
__launch_bounds__(256)
__global__ void k_agg(const int* __restrict__ row_start, const int* __restrict__ row_end,
                      const int* __restrict__ sorted_src,
                      const float* __restrict__ a_src, const float* __restrict__ a_dst,
                      const unsigned short* __restrict__ hb,
                      const float* __restrict__ bias_gat,
                      unsigned short* __restrict__ gb, int N) {
    int n = blockIdx.x * 4 + (threadIdx.x >> 6);
    if (n >= N) return;
    int lane = threadIdx.x & 63;
    int hd = lane >> 3;
    int start = row_start[n], end = row_end[n];
    float ad = a_dst[(size_t)n * 8 + hd];
    float ax = 0.f, ay = 0.f, az = 0.f, aw = 0.f, den = 0.f;
    float bx = 0.f, by = 0.f, bz = 0.f, bw = 0.f, den2 = 0.f;
    for (int j0 = start; j0 < end; j0 += 64) {
        int idx = j0 + lane;
        int sv = (idx < end) ? sorted_src[idx] : 0;
        int cnt = end - j0; if (cnt > 64) cnt = 64;
        int jj = 0;
        for (; jj + 3 < cnt; jj += 4) {
            int s0 = __shfl(sv, jj);
            int s1 = __shfl(sv, jj + 1);
            int s2 = __shfl(sv, jj + 2);
            int s3 = __shfl(sv, jj + 3);
            float v0 = a_src[(size_t)s0 * 8 + hd] + ad;
            float v1 = a_src[(size_t)s1 * 8 + hd] + ad;
            float v2 = a_src[(size_t)s2 * 8 + hd] + ad;
            float v3 = a_src[(size_t)s3 * 8 + hd] + ad;
            ushort4 h0 = *reinterpret_cast<const ushort4*>(hb + (size_t)s0 * 256 + lane * 4);
            ushort4 h1 = *reinterpret_cast<const ushort4*>(hb + (size_t)s1 * 256 + lane * 4);
            ushort4 h2 = *reinterpret_cast<const ushort4*>(hb + (size_t)s2 * 256 + lane * 4);
            ushort4 h3 = *reinterpret_cast<const ushort4*>(hb + (size_t)s3 * 256 + lane * 4);
            v0 = v0 > 0.f ? v0 : 0.2f * v0;
            v1 = v1 > 0.f ? v1 : 0.2f * v1;
            v2 = v2 > 0.f ? v2 : 0.2f * v2;
            v3 = v3 > 0.f ? v3 : 0.2f * v3;
            float e0 = __expf(v0), e1 = __expf(v1), e2 = __expf(v2), e3 = __expf(v3);
            den  += e0 + e2; den2 += e1 + e3;
            ax += e0 * b2f(h0.x); ay += e0 * b2f(h0.y);
            az += e0 * b2f(h0.z); aw += e0 * b2f(h0.w);
            bx += e1 * b2f(h1.x); by += e1 * b2f(h1.y);
            bz += e1 * b2f(h1.z); bw += e1 * b2f(h1.w);
            ax += e2 * b2f(h2.x); ay += e2 * b2f(h2.y);
            az += e2 * b2f(h2.z); aw += e2 * b2f(h2.w);
            bx += e3 * b2f(h3.x); by += e3 * b2f(h3.y);
            bz += e3 * b2f(h3.z); bw += e3 * b2f(h3.w);
        }
        for (; jj < cnt; ++jj) {
            int s0 = __shfl(sv, jj);
            float v0 = a_src[(size_t)s0 * 8 + hd] + ad;
            v0 = v0 > 0.f ? v0 : 0.2f * v0;
            float e0 = __expf(v0);
            ushort4 h0 = *reinterpret_cast<const ushort4*>(hb + (size_t)s0 * 256 + lane * 4);
            den += e0;
            ax += e0 * b2f(h0.x); ay += e0 * b2f(h0.y);
            az += e0 * b2f(h0.z); aw += e0 * b2f(h0.w);
        }
    }
    float inv = 1.0f / (den + den2 + 1e-16f);
    float4 b4 = *reinterpret_cast<const float4*>(bias_gat + lane * 4);
    ushort4 o;
    o.x = f2bf(fmaxf((ax + bx) * inv + b4.x, 0.f));
    o.y = f2bf(fmaxf((ay + by) * inv + b4.y, 0.f));
    o.z = f2bf(fmaxf((az + bz) * inv + b4.z, 0.f));
    o.w = f2bf(fmaxf((aw + bw) * inv + b4.w, 0.f));
    reinterpret_cast<ushort4*>(gb)[(size_t)n * 64 + lane] = o;
}

extern "C" void kernel_launch(void* const* d_in, const int* in_sizes, int n_in,
                              void* d_out, int out_size, void* d_ws, size_t ws_size,
                              hipStream_t stream) {
    const float* x        = (const float*)d_in[0];
    const int*   ei       = (const int*)d_in[1];
    const float* W_gat    = (const float*)d_in[2];
    const float* att_src  = (const float*)d_in[3];
    const float* att_dst  = (const float*)d_in[4];
    const float* bias_gat = (const float*)d_in[5];
    const float* W_lin    = (const float*)d_in[6];
    const float* b_lin    = (const float*)d_in[7];
    float* out = (float*)d_out;

    const int N  = in_sizes[0] / 256;   // 50000
    const int E  = in_sizes[1] / 2;     // 800000
    const int EE = E + N;

    char* ws = (char*)d_ws;
    size_t off = 0;
    auto alloc = [&](size_t bytes) -> void* {
        void* p = ws + off;
        off = (off + bytes + 255) & ~(size_t)255;
        return p;
    };
    unsigned short* hb       = (unsigned short*)alloc((size_t)N * 256 * 2);
    float*          a_srcv   = (float*)alloc((size_t)N * 8 * 4);
    float*          a_dstv   = (float*)alloc((size_t)N * 8 * 4);
    int*            cnt      = (int*)alloc((size_t)N * 4);
    int*            rowst    = (int*)alloc((size_t)N * 4);
    int*            cursor   = (int*)alloc((size_t)N * 4);
    int*            bsum     = (int*)alloc(SCAN_NB * 4);
    int*            ssrc     = (int*)alloc((size_t)EE * 4);
    unsigned short* xb       = (unsigned short*)alloc((size_t)N * 256 * 2);  // reused as gb
    unsigned short* wb       = (unsigned short*)alloc(256 * 256 * 2);
    unsigned short* wlb      = (unsigned short*)alloc(256 * 64 * 2);

    hipMemsetAsync(cnt, 0, (size_t)N * 4, stream);

    // fused conversions + histogram
    k_prep<<<2048, 256, 0, stream>>>(x, xb, N * 256 / 4,
                                     W_gat, wb, 256 * 256 / 4,
                                     W_lin, wlb, 256 * 64 / 4,
                                     ei, cnt, E, EE);

    // counting-sort scan
    k_scan_a<<<SCAN_NB, 256, 0, stream>>>(cnt, bsum, N);
    k_scan_bc<<<SCAN_NB, 256, 0, stream>>>(cnt, bsum, rowst, cursor, N);

    // fused GEMM1(+attn epilogue) || scatter  (independent work, one dispatch)
    const int RB  = (N + 63) / 64;
    const int GB1 = RB * 4;
    const int SB  = (EE + 255) / 256;
    k_gs<<<GB1 + SB, 256, 0, stream>>>(xb, wb, att_src, att_dst, hb, a_srcv, a_dstv,
                                       N, RB, GB1, ei, cursor, ssrc, E, EE);

    // fused segment softmax + aggregate + bias + relu -> bf16 (into xb as gb)
    k_agg<<<(N + 3) / 4, 256, 0, stream>>>(rowst, cursor, ssrc, a_srcv, a_dstv, hb,
                                           bias_gat, xb, N);

    // GEMM2: out = g @ W_lin + b_lin
    dim3 g2((N + 63) / 64, 1);
    k_gemm<<<g2, 256, 0, stream>>>(xb, wlb, out, b_lin, N, 64);
}